// Round 5
// baseline (1156.745 us; speedup 1.0000x reference)
//
#include <hip/hip_runtime.h>

#define NN 100000
#define EE 1600000
#define DD 32
#define NBUK 196          // row buckets of 512 rows (b = r>>9), 196*512 = 100352
#define BROWS 512
#define TILE 2048         // edges per phase-A tile
#define NT 782            // ceil(EE/TILE)
#define BCAP2 10240       // pairs capacity/bucket (mean 8163, sd ~90 -> 23 sigma)
#define BSLOT 12288       // padded CSR entries/bucket (mean ~10450, sd ~200)

typedef unsigned int uint;
typedef unsigned short ushort;

__device__ __forceinline__ ushort f2b(float f) {            // fp32 -> bf16 RNE
    uint u = __float_as_uint(f);
    u += 0x7fffu + ((u >> 16) & 1u);
    return (ushort)(u >> 16);
}
__device__ __forceinline__ float b2f(ushort h) {
    return __uint_as_float((uint)h << 16);
}

// --- phase A: tile-synchronous partition of edges into 196 row-buckets ------
// Writes are contiguous per (tile, bucket) chunk -> near-line-granular.

__global__ void k_part(const int* __restrict__ ei, int* __restrict__ gtail,
                       int2* __restrict__ pairs) {
    __shared__ int hist[256];
    __shared__ int gbase[256];
    int t = threadIdx.x;
    hist[t] = 0;
    __syncthreads();
    int e0 = blockIdx.x * TILE;
    int r[8], c[8], rk[8], bb[8];
#pragma unroll
    for (int k = 0; k < 8; ++k) {
        int e = e0 + t + k * 256;
        bb[k] = -1;
        if (e < EE) {
            r[k] = ei[e]; c[k] = ei[EE + e];
            if (r[k] != c[k]) {
                bb[k] = r[k] >> 9;
                rk[k] = atomicAdd(&hist[bb[k]], 1);   // rank within (tile,bucket)
            }
        }
    }
    __syncthreads();
    if (t < NBUK) {
        int cnt = hist[t];
        gbase[t] = cnt ? atomicAdd(&gtail[t * 16], cnt) : 0;
    }
    __syncthreads();
#pragma unroll
    for (int k = 0; k < 8; ++k) {
        if (bb[k] >= 0) {
            int pos = gbase[bb[k]] + rk[k];
            if (pos < BCAP2) {
                int2 v; v.x = r[k]; v.y = c[k];
                pairs[bb[k] * BCAP2 + pos] = v;
            }
        }
    }
}

// --- phase B: per-bucket exact CSR (padded to x8 per row) built in LDS ------
// desc[n] = (entry_base/8) | (class<<24), class = ceil(min(deg,64)/8) in 0..8

__global__ void k_build2(const int* __restrict__ gtail, const int2* __restrict__ pairs,
                         int* __restrict__ cur, int* __restrict__ desc,
                         int2* __restrict__ ent) {
    __shared__ int lcnt[BROWS];
    __shared__ int loff[BROWS];
    __shared__ int part[256];
    __shared__ int slab[BSLOT];    // 48 KB
    int b = blockIdx.x, t = threadIdx.x;
    lcnt[t] = 0; lcnt[t + 256] = 0;
    __syncthreads();
    int cnt = gtail[b * 16]; if (cnt > BCAP2) cnt = BCAP2;
    const int2* pp = pairs + b * BCAP2;
    for (int i = t; i < cnt; i += 256)
        atomicAdd(&lcnt[pp[i].x & (BROWS - 1)], 1);
    __syncthreads();
    int v0 = lcnt[2 * t], v1 = lcnt[2 * t + 1];
    int s0 = v0 > 64 ? 64 : v0; s0 = (s0 + 7) & ~7;
    int s1 = v1 > 64 ? 64 : v1; s1 = (s1 + 7) & ~7;
    part[t] = s0 + s1;
    __syncthreads();
    for (int d = 1; d < 256; d <<= 1) {           // Hillis-Steele inclusive scan
        int x = part[t];
        int y = (t >= d) ? part[t - d] : 0;
        __syncthreads();
        part[t] = x + y;
        __syncthreads();
    }
    int excl = (t == 0) ? 0 : part[t - 1];
    loff[2 * t] = excl;
    loff[2 * t + 1] = excl + s0;
    __syncthreads();
    int rowbase = b * BROWS;
    for (int lr = t; lr < BROWS; lr += 256) {     // write degree + descriptor
        int n = rowbase + lr;
        if (n < NN) {
            int d = lcnt[lr];
            int ms = d > 64 ? 64 : d;
            int cls = (ms + 7) >> 3;
            cur[n] = d;
            desc[n] = ((b * BSLOT + loff[lr]) >> 3) | (cls << 24);
        }
    }
    __syncthreads();
    lcnt[t] = 0; lcnt[t + 256] = 0;               // reuse as write cursor
    for (int i = t; i < BSLOT; i += 256) slab[i] = -1;  // -1 marks pad slots
    __syncthreads();
    for (int i = t; i < cnt; i += 256) {
        int2 pr = pp[i];
        int lr = pr.x & (BROWS - 1);
        int pos = atomicAdd(&lcnt[lr], 1);
        if (pos < 64) slab[loff[lr] + pos] = pr.y;
    }
    __syncthreads();
    int padded = part[255];
    for (int i = t; i < padded; i += 256) {       // fully coalesced stream-out
        int2 e; e.x = slab[i]; e.y = 0;
        ent[(size_t)b * BSLOT + i] = e;
    }
}

__global__ void k_dinv(const int* __restrict__ cur, float* __restrict__ dinv) {
    int n = blockIdx.x * blockDim.x + threadIdx.x;
    if (n >= NN) return;
    int d = cur[n];
    dinv[n] = d > 0 ? rsqrtf((float)d) : 0.0f;
}

// --- weight fill: ent[i] = { col<<2, w_fp32 }; pad slots (-1) -> {0, 0} -----

__global__ void k_wfill(const float* __restrict__ dinv, const int* __restrict__ desc,
                        int2* __restrict__ ent) {
    int tid = blockIdx.x * blockDim.x + threadIdx.x;
    int n = tid >> 3, lane = tid & 7;
    if (n >= NN) return;
    int d = desc[n];
    int base = (d & 0xFFFFFF) << 3;
    int mr = ((d >> 24) & 15) << 3;
    float dr = dinv[n];
    for (int k = lane; k < mr; k += 8) {
        int2 e = ent[base + k];
        int2 o;
        if (e.x < 0) { o.x = 0; o.y = 0; }
        else { o.x = e.x << 2; o.y = __float_as_int(-dr * dinv[e.x]); }
        ent[base + k] = o;
    }
}

// --- degree-class counting sort: pdesc[g] = {node, desc} in class order -----

__global__ void k_hist(const int* __restrict__ desc, int* __restrict__ ghist) {
    __shared__ int h[16];
    if (threadIdx.x < 16) h[threadIdx.x] = 0;
    __syncthreads();
    int n = blockIdx.x * blockDim.x + threadIdx.x;
    if (n < NN) atomicAdd(&h[(desc[n] >> 24) & 15], 1);
    __syncthreads();
    if (threadIdx.x < 16 && h[threadIdx.x])
        atomicAdd(&ghist[threadIdx.x], h[threadIdx.x]);
}

__global__ void k_scan(const int* __restrict__ ghist, int* __restrict__ classcur) {
    int s = 0;
    for (int i = 0; i < 16; ++i) { classcur[i] = s; s += ghist[i]; }
}

__global__ void k_perms(const int* __restrict__ desc, int* __restrict__ classcur,
                        int2* __restrict__ pdesc) {
    int n = blockIdx.x * blockDim.x + threadIdx.x;
    if (n >= NN) return;
    int d = desc[n];
    int pos = atomicAdd(&classcur[(d >> 24) & 15], 1);
    int2 v; v.x = n; v.y = d;
    pdesc[pos] = v;
}

// --- fp32 x -> bf16 table ----------------------------------------------------

__global__ void k_cvt(const float* __restrict__ x, uint* __restrict__ xb) {
    int tid = blockIdx.x * blockDim.x + threadIdx.x;
    if (tid >= NN * DD / 2) return;
    float2 v = ((const float2*)x)[tid];
    xb[tid] = (uint)f2b(v.x) | ((uint)f2b(v.y) << 16);
}

// --- propagation (degree-sorted): 4 lanes/node, 16B gathers, unroll-8 -------

__global__ void k_prop(const int2* __restrict__ pdesc, const int2* __restrict__ ent,
                       const uint4* __restrict__ srcq, const uint4* __restrict__ baseq,
                       uint4* __restrict__ dstq, float alpha, float beta) {
    int tid = blockIdx.x * blockDim.x + threadIdx.x;
    int g = tid >> 2, sub = tid & 3;
    if (g >= NN) return;
    int2 pd = pdesc[g];
    int n = pd.x;
    const int2* ep = ent + ((size_t)(pd.y & 0xFFFFFF) << 3);
    int mr = ((pd.y >> 24) & 15) << 3;
    float acc[8] = {0, 0, 0, 0, 0, 0, 0, 0};
    for (int i = 0; i < mr; i += 8) {
#pragma unroll
        for (int j = 0; j < 8; ++j) {
            int2 e = ep[i + j];                 // 8B quad-broadcast (one line/8 entries)
            float w = __int_as_float(e.y);
            uint4 v = srcq[e.x + sub];          // random 16B segment (64B line/node)
            acc[0] += w * __uint_as_float(v.x << 16);
            acc[1] += w * __uint_as_float(v.x & 0xffff0000u);
            acc[2] += w * __uint_as_float(v.y << 16);
            acc[3] += w * __uint_as_float(v.y & 0xffff0000u);
            acc[4] += w * __uint_as_float(v.z << 16);
            acc[5] += w * __uint_as_float(v.z & 0xffff0000u);
            acc[6] += w * __uint_as_float(v.w << 16);
            acc[7] += w * __uint_as_float(v.w & 0xffff0000u);
        }
    }
#pragma unroll
    for (int k = 0; k < 8; ++k) acc[k] *= alpha;
    int o4 = (n << 2) + sub;
    if (baseq) {
        uint4 bq = baseq[o4];
        acc[0] += beta * __uint_as_float(bq.x << 16);
        acc[1] += beta * __uint_as_float(bq.x & 0xffff0000u);
        acc[2] += beta * __uint_as_float(bq.y << 16);
        acc[3] += beta * __uint_as_float(bq.y & 0xffff0000u);
        acc[4] += beta * __uint_as_float(bq.z << 16);
        acc[5] += beta * __uint_as_float(bq.z & 0xffff0000u);
        acc[6] += beta * __uint_as_float(bq.w << 16);
        acc[7] += beta * __uint_as_float(bq.w & 0xffff0000u);
    }
    uint4 o;
    o.x = (uint)f2b(acc[0]) | ((uint)f2b(acc[1]) << 16);
    o.y = (uint)f2b(acc[2]) | ((uint)f2b(acc[3]) << 16);
    o.z = (uint)f2b(acc[4]) | ((uint)f2b(acc[5]) << 16);
    o.w = (uint)f2b(acc[6]) | ((uint)f2b(acc[7]) << 16);
    dstq[o4] = o;
}

// --- dense mix from bf16 T's: out = act(sum_k Tk @ Wk + b) (+fp32 resid) ----

__global__ void k_combine(const ushort* __restrict__ t0, const ushort* __restrict__ t1,
                          const ushort* __restrict__ t2, const float* __restrict__ W,
                          const float* __restrict__ bias, const float* __restrict__ residf,
                          float* __restrict__ outf, ushort* __restrict__ outb,
                          int do_relu) {
    __shared__ float Ws[3 * DD * DD];
    for (int i = threadIdx.x; i < 3 * DD * DD; i += blockDim.x) Ws[i] = W[i];
    __syncthreads();
    int tid = blockIdx.x * blockDim.x + threadIdx.x;
    int n = tid >> 5, j = tid & 31;
    if (n >= NN) return;
    float v0 = b2f(t0[tid]), v1 = b2f(t1[tid]), v2 = b2f(t2[tid]);
    float acc = bias[j];
#pragma unroll
    for (int i = 0; i < DD; ++i) {
        float a0 = __shfl(v0, i, 32);
        float a1 = __shfl(v1, i, 32);
        float a2 = __shfl(v2, i, 32);
        acc += a0 * Ws[i * DD + j]
             + a1 * Ws[DD * DD + i * DD + j]
             + a2 * Ws[2 * DD * DD + i * DD + j];
    }
    if (do_relu) acc = fmaxf(acc, 0.0f);
    if (residf) acc += residf[tid];
    if (outf) outf[tid] = acc;
    if (outb) outb[tid] = f2b(acc);
}

// --- launch ------------------------------------------------------------------

extern "C" void kernel_launch(void* const* d_in, const int* in_sizes, int n_in,
                              void* d_out, int out_size, void* d_ws, size_t ws_size,
                              hipStream_t stream) {
    const float* x  = (const float*)d_in[0];
    const int*   ei = (const int*)d_in[1];
    const float* W1 = (const float*)d_in[2];
    const float* b1 = (const float*)d_in[3];
    const float* W2 = (const float*)d_in[4];
    const float* b2 = (const float*)d_in[5];
    float* out = (float*)d_out;

    char* wsp = (char*)d_ws;
    size_t off = 0;
    auto take = [&](size_t bytes) {
        char* p = wsp + off;
        off = (off + bytes + 255) & ~(size_t)255;
        return p;
    };
    int*    ctrl  = (int*)take((size_t)(NBUK * 16 + 32) * 4);    // gtail | ghist | classcur
    int*    gtail = ctrl;
    int*    ghist = ctrl + NBUK * 16;
    int*    ccur  = ctrl + NBUK * 16 + 16;
    int*    cur   = (int*)take((size_t)NN * 4);
    float*  dinv  = (float*)take((size_t)NN * 4);
    int*    desc  = (int*)take((size_t)NN * 4);
    int2*   pdesc = (int2*)take((size_t)NN * 8);
    int2*   pairs = (int2*)take((size_t)NBUK * BCAP2 * 8);       // 16.1 MB
    int2*   ent   = (int2*)take((size_t)NBUK * BSLOT * 8);       // 19.3 MB
    ushort* xb    = (ushort*)take((size_t)NN * DD * 2);          // 6.4 MB
    ushort* t1b   = (ushort*)take((size_t)NN * DD * 2);
    ushort* t2b   = (ushort*)take((size_t)NN * DD * 2);
    ushort* hb    = (ushort*)take((size_t)NN * DD * 2);
    // total ~63 MB

    hipMemsetAsync(ctrl, 0, (size_t)(NBUK * 16 + 32) * 4, stream);

    k_part  <<<NT, 256, 0, stream>>>(ei, gtail, pairs);
    k_build2<<<NBUK, 256, 0, stream>>>(gtail, pairs, cur, desc, ent);
    k_dinv  <<<(NN + 255) / 256, 256, 0, stream>>>(cur, dinv);
    k_wfill <<<(NN * 8) / 256 + 1, 256, 0, stream>>>(dinv, desc, ent);
    k_hist  <<<(NN + 255) / 256, 256, 0, stream>>>(desc, ghist);
    k_scan  <<<1, 1, 0, stream>>>(ghist, ccur);
    k_perms <<<(NN + 255) / 256, 256, 0, stream>>>(desc, ccur, pdesc);
    k_cvt   <<<NN * DD / 2 / 256, 256, 0, stream>>>(x, (uint*)xb);

    const int pgrid = (NN * 4 + 255) / 256;   // 1563
    const int cgrid = NN * DD / 256;          // 12500
    // layer 1: Tx0 = x
    k_prop<<<pgrid, 256, 0, stream>>>(pdesc, ent, (const uint4*)xb,  nullptr,
                                      (uint4*)t1b, 1.0f, 0.0f);
    k_prop<<<pgrid, 256, 0, stream>>>(pdesc, ent, (const uint4*)t1b, (const uint4*)xb,
                                      (uint4*)t2b, 2.0f, -1.0f);
    k_combine<<<cgrid, 256, 0, stream>>>(xb, t1b, t2b, W1, b1, nullptr, nullptr, hb, 1);
    // layer 2: Tx0 = h
    k_prop<<<pgrid, 256, 0, stream>>>(pdesc, ent, (const uint4*)hb,  nullptr,
                                      (uint4*)t1b, 1.0f, 0.0f);
    k_prop<<<pgrid, 256, 0, stream>>>(pdesc, ent, (const uint4*)t1b, (const uint4*)hb,
                                      (uint4*)t2b, 2.0f, -1.0f);
    k_combine<<<cgrid, 256, 0, stream>>>(hb, t1b, t2b, W2, b2, x, out, nullptr, 0);
}

// Round 6
// 409.088 us; speedup vs baseline: 2.8276x; 2.8276x over previous
//
#include <hip/hip_runtime.h>

#define NN 100000
#define EE 1600000
#define DD 32
#define NBUK 196          // row buckets of 512 rows (b = r>>9), 196*512 = 100352
#define BROWS 512
#define TILE 2048         // edges per phase-A tile
#define NT 782            // ceil(EE/TILE)
#define BCAP2 10240       // pairs capacity/bucket (mean 8163, sd ~90 -> 23 sigma)
#define BSLOT 12288       // padded CSR entries/bucket (mean ~10450, sd ~200)

typedef unsigned int uint;
typedef unsigned short ushort;

__device__ __forceinline__ ushort f2b(float f) {            // fp32 -> bf16 RNE
    uint u = __float_as_uint(f);
    u += 0x7fffu + ((u >> 16) & 1u);
    return (ushort)(u >> 16);
}
__device__ __forceinline__ float b2f(ushort h) {
    return __uint_as_float((uint)h << 16);
}

// --- phase A: tile-synchronous partition of edges into 196 row-buckets ------
// Writes are contiguous per (tile, bucket) chunk -> near-line-granular.

__global__ void k_part(const int* __restrict__ ei, int* __restrict__ gtail,
                       int2* __restrict__ pairs) {
    __shared__ int hist[256];
    __shared__ int gbase[256];
    int t = threadIdx.x;
    hist[t] = 0;
    __syncthreads();
    int e0 = blockIdx.x * TILE;
    int r[8], c[8], rk[8], bb[8];
#pragma unroll
    for (int k = 0; k < 8; ++k) {
        int e = e0 + t + k * 256;
        bb[k] = -1;
        if (e < EE) {
            r[k] = ei[e]; c[k] = ei[EE + e];
            if (r[k] != c[k]) {
                bb[k] = r[k] >> 9;
                rk[k] = atomicAdd(&hist[bb[k]], 1);   // rank within (tile,bucket)
            }
        }
    }
    __syncthreads();
    if (t < NBUK) {
        int cnt = hist[t];
        gbase[t] = cnt ? atomicAdd(&gtail[t * 16], cnt) : 0;
    }
    __syncthreads();
#pragma unroll
    for (int k = 0; k < 8; ++k) {
        if (bb[k] >= 0) {
            int pos = gbase[bb[k]] + rk[k];
            if (pos < BCAP2) {
                int2 v; v.x = r[k]; v.y = c[k];
                pairs[bb[k] * BCAP2 + pos] = v;
            }
        }
    }
}

// --- phase B: per-bucket exact CSR (padded to x8 per row) built in LDS ------
// desc[n] = (entry_base/8) | (class<<24), class = ceil(min(deg,64)/8) in 0..8

__global__ void k_build2(const int* __restrict__ gtail, const int2* __restrict__ pairs,
                         int* __restrict__ cur, int* __restrict__ desc,
                         int2* __restrict__ ent) {
    __shared__ int lcnt[BROWS];
    __shared__ int loff[BROWS];
    __shared__ int part[256];
    __shared__ int slab[BSLOT];    // 48 KB
    int b = blockIdx.x, t = threadIdx.x;
    lcnt[t] = 0; lcnt[t + 256] = 0;
    __syncthreads();
    int cnt = gtail[b * 16]; if (cnt > BCAP2) cnt = BCAP2;
    const int2* pp = pairs + b * BCAP2;
    for (int i = t; i < cnt; i += 256)
        atomicAdd(&lcnt[pp[i].x & (BROWS - 1)], 1);
    __syncthreads();
    int v0 = lcnt[2 * t], v1 = lcnt[2 * t + 1];
    int s0 = v0 > 64 ? 64 : v0; s0 = (s0 + 7) & ~7;
    int s1 = v1 > 64 ? 64 : v1; s1 = (s1 + 7) & ~7;
    part[t] = s0 + s1;
    __syncthreads();
    for (int d = 1; d < 256; d <<= 1) {           // Hillis-Steele inclusive scan
        int x = part[t];
        int y = (t >= d) ? part[t - d] : 0;
        __syncthreads();
        part[t] = x + y;
        __syncthreads();
    }
    int excl = (t == 0) ? 0 : part[t - 1];
    loff[2 * t] = excl;
    loff[2 * t + 1] = excl + s0;
    __syncthreads();
    int rowbase = b * BROWS;
    for (int lr = t; lr < BROWS; lr += 256) {     // write degree + descriptor
        int n = rowbase + lr;
        if (n < NN) {
            int d = lcnt[lr];
            int ms = d > 64 ? 64 : d;
            int cls = (ms + 7) >> 3;
            cur[n] = d;
            desc[n] = ((b * BSLOT + loff[lr]) >> 3) | (cls << 24);
        }
    }
    __syncthreads();
    lcnt[t] = 0; lcnt[t + 256] = 0;               // reuse as write cursor
    for (int i = t; i < BSLOT; i += 256) slab[i] = -1;  // -1 marks pad slots
    __syncthreads();
    for (int i = t; i < cnt; i += 256) {
        int2 pr = pp[i];
        int lr = pr.x & (BROWS - 1);
        int pos = atomicAdd(&lcnt[lr], 1);
        if (pos < 64) slab[loff[lr] + pos] = pr.y;
    }
    __syncthreads();
    int padded = part[255];
    for (int i = t; i < padded; i += 256) {       // fully coalesced stream-out
        int2 e; e.x = slab[i]; e.y = 0;
        ent[(size_t)b * BSLOT + i] = e;
    }
}

__global__ void k_dinv(const int* __restrict__ cur, float* __restrict__ dinv) {
    int n = blockIdx.x * blockDim.x + threadIdx.x;
    if (n >= NN) return;
    int d = cur[n];
    dinv[n] = d > 0 ? rsqrtf((float)d) : 0.0f;
}

// --- weight fill: ent[i] = { col<<2, w_fp32 }; pad slots (-1) -> {0, 0} -----

__global__ void k_wfill(const float* __restrict__ dinv, const int* __restrict__ desc,
                        int2* __restrict__ ent) {
    int tid = blockIdx.x * blockDim.x + threadIdx.x;
    int n = tid >> 3, lane = tid & 7;
    if (n >= NN) return;
    int d = desc[n];
    int base = (d & 0xFFFFFF) << 3;
    int mr = ((d >> 24) & 15) << 3;
    float dr = dinv[n];
    for (int k = lane; k < mr; k += 8) {
        int2 e = ent[base + k];
        int2 o;
        if (e.x < 0) { o.x = 0; o.y = 0; }
        else { o.x = e.x << 2; o.y = __float_as_int(-dr * dinv[e.x]); }
        ent[base + k] = o;
    }
}

// --- degree-class counting sort ----------------------------------------------
// k_perms is BLOCK-AGGREGATED: <=16 global atomics per block (R5's per-thread
// version serialized 100K atomics on 9 addresses -> 750 us).

__global__ void k_hist(const int* __restrict__ desc, int* __restrict__ ghist) {
    __shared__ int h[16];
    if (threadIdx.x < 16) h[threadIdx.x] = 0;
    __syncthreads();
    int n = blockIdx.x * blockDim.x + threadIdx.x;
    if (n < NN) atomicAdd(&h[(desc[n] >> 24) & 15], 1);
    __syncthreads();
    if (threadIdx.x < 16 && h[threadIdx.x])
        atomicAdd(&ghist[threadIdx.x], h[threadIdx.x]);
}

__global__ void k_scan(const int* __restrict__ ghist, int* __restrict__ classcur) {
    int s = 0;
    for (int i = 0; i < 16; ++i) { classcur[i] = s; s += ghist[i]; }
}

__global__ void k_perms(const int* __restrict__ desc, int* __restrict__ classcur,
                        int2* __restrict__ pdesc) {
    __shared__ int h[16];
    __shared__ int base[16];
    if (threadIdx.x < 16) h[threadIdx.x] = 0;
    __syncthreads();
    int n = blockIdx.x * blockDim.x + threadIdx.x;
    int d = 0, cls = 0, rk = 0;
    if (n < NN) {
        d = desc[n];
        cls = (d >> 24) & 15;
        rk = atomicAdd(&h[cls], 1);               // LDS atomic: cheap
    }
    __syncthreads();
    if (threadIdx.x < 16 && h[threadIdx.x])
        base[threadIdx.x] = atomicAdd(&classcur[threadIdx.x], h[threadIdx.x]);
    __syncthreads();
    if (n < NN) {
        int2 v; v.x = n; v.y = d;
        pdesc[base[cls] + rk] = v;                // contiguous per-class runs
    }
}

// --- fp32 x -> bf16 table ----------------------------------------------------

__global__ void k_cvt(const float* __restrict__ x, uint* __restrict__ xb) {
    int tid = blockIdx.x * blockDim.x + threadIdx.x;
    if (tid >= NN * DD / 2) return;
    float2 v = ((const float2*)x)[tid];
    xb[tid] = (uint)f2b(v.x) | ((uint)f2b(v.y) << 16);
}

// --- propagation (degree-sorted): 4 lanes/node, 16B gathers, unroll-8 -------

__global__ void k_prop(const int2* __restrict__ pdesc, const int2* __restrict__ ent,
                       const uint4* __restrict__ srcq, const uint4* __restrict__ baseq,
                       uint4* __restrict__ dstq, float alpha, float beta) {
    int tid = blockIdx.x * blockDim.x + threadIdx.x;
    int g = tid >> 2, sub = tid & 3;
    if (g >= NN) return;
    int2 pd = pdesc[g];
    int n = pd.x;
    const int2* ep = ent + ((size_t)(pd.y & 0xFFFFFF) << 3);
    int mr = ((pd.y >> 24) & 15) << 3;
    float acc[8] = {0, 0, 0, 0, 0, 0, 0, 0};
    for (int i = 0; i < mr; i += 8) {
#pragma unroll
        for (int j = 0; j < 8; ++j) {
            int2 e = ep[i + j];                 // 8B quad-broadcast (one line/8 entries)
            float w = __int_as_float(e.y);
            uint4 v = srcq[e.x + sub];          // random 16B segment (64B line/node)
            acc[0] += w * __uint_as_float(v.x << 16);
            acc[1] += w * __uint_as_float(v.x & 0xffff0000u);
            acc[2] += w * __uint_as_float(v.y << 16);
            acc[3] += w * __uint_as_float(v.y & 0xffff0000u);
            acc[4] += w * __uint_as_float(v.z << 16);
            acc[5] += w * __uint_as_float(v.z & 0xffff0000u);
            acc[6] += w * __uint_as_float(v.w << 16);
            acc[7] += w * __uint_as_float(v.w & 0xffff0000u);
        }
    }
#pragma unroll
    for (int k = 0; k < 8; ++k) acc[k] *= alpha;
    int o4 = (n << 2) + sub;
    if (baseq) {
        uint4 bq = baseq[o4];
        acc[0] += beta * __uint_as_float(bq.x << 16);
        acc[1] += beta * __uint_as_float(bq.x & 0xffff0000u);
        acc[2] += beta * __uint_as_float(bq.y << 16);
        acc[3] += beta * __uint_as_float(bq.y & 0xffff0000u);
        acc[4] += beta * __uint_as_float(bq.z << 16);
        acc[5] += beta * __uint_as_float(bq.z & 0xffff0000u);
        acc[6] += beta * __uint_as_float(bq.w << 16);
        acc[7] += beta * __uint_as_float(bq.w & 0xffff0000u);
    }
    uint4 o;
    o.x = (uint)f2b(acc[0]) | ((uint)f2b(acc[1]) << 16);
    o.y = (uint)f2b(acc[2]) | ((uint)f2b(acc[3]) << 16);
    o.z = (uint)f2b(acc[4]) | ((uint)f2b(acc[5]) << 16);
    o.w = (uint)f2b(acc[6]) | ((uint)f2b(acc[7]) << 16);
    dstq[o4] = o;
}

// --- dense mix from bf16 T's: out = act(sum_k Tk @ Wk + b) (+fp32 resid) ----

__global__ void k_combine(const ushort* __restrict__ t0, const ushort* __restrict__ t1,
                          const ushort* __restrict__ t2, const float* __restrict__ W,
                          const float* __restrict__ bias, const float* __restrict__ residf,
                          float* __restrict__ outf, ushort* __restrict__ outb,
                          int do_relu) {
    __shared__ float Ws[3 * DD * DD];
    for (int i = threadIdx.x; i < 3 * DD * DD; i += blockDim.x) Ws[i] = W[i];
    __syncthreads();
    int tid = blockIdx.x * blockDim.x + threadIdx.x;
    int n = tid >> 5, j = tid & 31;
    if (n >= NN) return;
    float v0 = b2f(t0[tid]), v1 = b2f(t1[tid]), v2 = b2f(t2[tid]);
    float acc = bias[j];
#pragma unroll
    for (int i = 0; i < DD; ++i) {
        float a0 = __shfl(v0, i, 32);
        float a1 = __shfl(v1, i, 32);
        float a2 = __shfl(v2, i, 32);
        acc += a0 * Ws[i * DD + j]
             + a1 * Ws[DD * DD + i * DD + j]
             + a2 * Ws[2 * DD * DD + i * DD + j];
    }
    if (do_relu) acc = fmaxf(acc, 0.0f);
    if (residf) acc += residf[tid];
    if (outf) outf[tid] = acc;
    if (outb) outb[tid] = f2b(acc);
}

// --- launch ------------------------------------------------------------------

extern "C" void kernel_launch(void* const* d_in, const int* in_sizes, int n_in,
                              void* d_out, int out_size, void* d_ws, size_t ws_size,
                              hipStream_t stream) {
    const float* x  = (const float*)d_in[0];
    const int*   ei = (const int*)d_in[1];
    const float* W1 = (const float*)d_in[2];
    const float* b1 = (const float*)d_in[3];
    const float* W2 = (const float*)d_in[4];
    const float* b2 = (const float*)d_in[5];
    float* out = (float*)d_out;

    char* wsp = (char*)d_ws;
    size_t off = 0;
    auto take = [&](size_t bytes) {
        char* p = wsp + off;
        off = (off + bytes + 255) & ~(size_t)255;
        return p;
    };
    int*    ctrl  = (int*)take((size_t)(NBUK * 16 + 32) * 4);    // gtail | ghist | classcur
    int*    gtail = ctrl;
    int*    ghist = ctrl + NBUK * 16;
    int*    ccur  = ctrl + NBUK * 16 + 16;
    int*    cur   = (int*)take((size_t)NN * 4);
    float*  dinv  = (float*)take((size_t)NN * 4);
    int*    desc  = (int*)take((size_t)NN * 4);
    int2*   pdesc = (int2*)take((size_t)NN * 8);
    int2*   pairs = (int2*)take((size_t)NBUK * BCAP2 * 8);       // 16.1 MB
    int2*   ent   = (int2*)take((size_t)NBUK * BSLOT * 8);       // 19.3 MB
    ushort* xb    = (ushort*)take((size_t)NN * DD * 2);          // 6.4 MB
    ushort* t1b   = (ushort*)take((size_t)NN * DD * 2);
    ushort* t2b   = (ushort*)take((size_t)NN * DD * 2);
    ushort* hb    = (ushort*)take((size_t)NN * DD * 2);
    // total ~63 MB

    hipMemsetAsync(ctrl, 0, (size_t)(NBUK * 16 + 32) * 4, stream);

    k_part  <<<NT, 256, 0, stream>>>(ei, gtail, pairs);
    k_build2<<<NBUK, 256, 0, stream>>>(gtail, pairs, cur, desc, ent);
    k_dinv  <<<(NN + 255) / 256, 256, 0, stream>>>(cur, dinv);
    k_wfill <<<(NN * 8) / 256 + 1, 256, 0, stream>>>(dinv, desc, ent);
    k_hist  <<<(NN + 255) / 256, 256, 0, stream>>>(desc, ghist);
    k_scan  <<<1, 1, 0, stream>>>(ghist, ccur);
    k_perms <<<(NN + 255) / 256, 256, 0, stream>>>(desc, ccur, pdesc);
    k_cvt   <<<NN * DD / 2 / 256, 256, 0, stream>>>(x, (uint*)xb);

    const int pgrid = (NN * 4 + 255) / 256;   // 1563
    const int cgrid = NN * DD / 256;          // 12500
    // layer 1: Tx0 = x
    k_prop<<<pgrid, 256, 0, stream>>>(pdesc, ent, (const uint4*)xb,  nullptr,
                                      (uint4*)t1b, 1.0f, 0.0f);
    k_prop<<<pgrid, 256, 0, stream>>>(pdesc, ent, (const uint4*)t1b, (const uint4*)xb,
                                      (uint4*)t2b, 2.0f, -1.0f);
    k_combine<<<cgrid, 256, 0, stream>>>(xb, t1b, t2b, W1, b1, nullptr, nullptr, hb, 1);
    // layer 2: Tx0 = h
    k_prop<<<pgrid, 256, 0, stream>>>(pdesc, ent, (const uint4*)hb,  nullptr,
                                      (uint4*)t1b, 1.0f, 0.0f);
    k_prop<<<pgrid, 256, 0, stream>>>(pdesc, ent, (const uint4*)t1b, (const uint4*)hb,
                                      (uint4*)t2b, 2.0f, -1.0f);
    k_combine<<<cgrid, 256, 0, stream>>>(hb, t1b, t2b, W2, b2, x, out, nullptr, 0);
}